// Round 5
// baseline (324.872 us; speedup 1.0000x reference)
//
#include <hip/hip_runtime.h>
#include <math.h>

#define B_ 4
#define N_ 512
#define D_ 64
#define NDIAG (2 * N_ - 1)   // 1023 diagonal rows of D
#define WV 4                 // waves per block
#define K_ 16                // diagonals per chunk (between barriers)
#define DC0 9                // chunk stagger between adjacent waves
#define NCH 40               // chunks per wave
#define CTOT (DC0 * (WV - 1) + NCH)  // 67
#define RING 1028            // non-wrapping ring: one slot per diagonal
#define BIGF 1e30f           // finite border sentinel: BIG + d rounds to BIG

// Phase 1: D[b][i][j] = ||x[b,i,:]-y[b,j,:]||, stored diagonal-major
__global__ __launch_bounds__(256) void dist_diag_kernel(
    const float* __restrict__ x, const float* __restrict__ y,
    float* __restrict__ ddiag)
{
    const int b = blockIdx.z;
    const int i0 = blockIdx.y * 16;
    const int j0 = blockIdx.x * 16;
    __shared__ float xs[16 * 68];
    __shared__ float ys[16 * 68];
    const int t = threadIdx.x;
    const int lr = t >> 4;
    const int lc = t & 15;
    const float4* xsrc = (const float4*)(x + (((size_t)b * N_) + i0 + lr) * D_);
    const float4* ysrc = (const float4*)(y + (((size_t)b * N_) + j0 + lr) * D_);
    *(float4*)(&xs[lr * 68 + lc * 4]) = xsrc[lc];
    *(float4*)(&ys[lr * 68 + lc * 4]) = ysrc[lc];
    __syncthreads();

    const int ti = t >> 4, tj = t & 15;
    const float* xr = &xs[ti * 68];
    const float* yr = &ys[tj * 68];
    float acc = 0.f;
#pragma unroll
    for (int k = 0; k < 16; ++k) {
        float4 a = *(const float4*)(xr + 4 * k);
        float4 c = *(const float4*)(yr + 4 * k);
        float d0 = a.x - c.x, d1 = a.y - c.y, d2 = a.z - c.z, d3 = a.w - c.w;
        acc += d0 * d0 + d1 * d1 + d2 * d2 + d3 * d3;
    }
    const int i = i0 + ti, j = j0 + tj;
    ddiag[((size_t)b * NDIAG + (size_t)(i + j)) * N_ + j] = sqrtf(acc);
}

__device__ __forceinline__ float dpp_shr1(float x) {
    int v = __builtin_amdgcn_update_dpp(0x7f800000, __float_as_int(x),
                                        0x138 /*WAVE_SHR1*/, 0xf, 0xf, false);
    return __int_as_float(v);
}

__device__ __forceinline__ float vmin3(float a, float b, float c) {
    float r; asm("v_min3_f32 %0, %1, %2, %3" : "=v"(r) : "v"(a), "v"(b), "v"(c)); return r;
}
__device__ __forceinline__ float vmed3(float a, float b, float c) {
    float r; asm("v_med3_f32 %0, %1, %2, %3" : "=v"(r) : "v"(a), "v"(b), "v"(c)); return r;
}
__device__ __forceinline__ float vmax3(float a, float b, float c) {
    float r; asm("v_max3_f32 %0, %1, %2, %3" : "=v"(r) : "v"(a), "v"(b), "v"(c)); return r;
}

#if __has_builtin(__builtin_amdgcn_exp2f)
#define EXP2(x) __builtin_amdgcn_exp2f(x)
#else
#define EXP2(x) exp2f(x)
#endif
#if __has_builtin(__builtin_amdgcn_logf)
#define LOG2(x) __builtin_amdgcn_logf(x)
#else
#define LOG2(x) log2f(x)
#endif

__device__ __forceinline__ void gload_lds16(const float* g, float* lds) {
    __builtin_amdgcn_global_load_lds(
        (const __attribute__((address_space(1))) void*)g,
        (__attribute__((address_space(3))) void*)lds, 16, 0, 0);
}

// 2x2 ablation of the staggered soft-DTW:
//   V0: softmin + transport (EXACT — writes d_out)
//   V1: softmin, no transport (d = off-chain register)
//   V2: hardmin + transport
//   V3: hardmin, no transport (pure issue+DPP+barrier floor)
template <int V>
__global__ __launch_bounds__(256) void sdtw_probe(
    const float* __restrict__ ddiag, float* __restrict__ out,
    float* __restrict__ dump)
{
    constexpr bool SOFT  = (V == 0 || V == 1);
    constexpr bool XPORT = (V == 0 || V == 2);

    const int b = blockIdx.x;
    const int tid = threadIdx.x;
    const int w = tid >> 6;
    const int lane = tid & 63;
    const float* Db = ddiag + (size_t)b * (NDIAG * (size_t)N_);

    if constexpr (V == 0) {
        for (int q = tid; q < N_; q += 256) {
            out[b * N_ + q] = (float)q;
            out[B_ * N_ + b * N_ + q] = (float)q;
        }
    }

    __shared__ __align__(16) float ring[WV + 1][RING];
    __shared__ __align__(16) float dvs[WV][2][K_ * 128];
    for (int q = tid; q < (WV + 1) * RING; q += 256)
        (&ring[0][0])[q] = (q == 0) ? 0.0f : BIGF;
    __syncthreads();

    const float C1 = 14.4269504089f;
    const float C2 = -0.069314718056f;
    const int c0w = DC0 * w;
    const int s0w = 128 * w + 2;
    const bool l0 = (lane == 0);
    const bool l63 = (lane == 63);
    const float* ringR = ring[w];
    float* ringW = ring[w + 1];
    const int colbase = 128 * w;
    const unsigned lq = lane & 31u, lp = (unsigned)lane >> 5;

    // off-chain runtime value for no-transport variants (prevents const-fold)
    float dval = 1.0f;
    if constexpr (!XPORT) dval = Db[lane];

#define STAGE(lc_, buf_)                                                   \
    {                                                                      \
        const int s0_ = s0w + (lc_) * K_;                                  \
        _Pragma("unroll")                                                  \
        for (int p = 0; p < 8; ++p) {                                      \
            int row_ = s0_ - 2 + 2 * p + (int)lp;                          \
            row_ = row_ > (NDIAG - 1) ? (NDIAG - 1) : row_;                \
            const float* g_ = Db + (size_t)row_ * N_ + colbase + lq * 4;   \
            gload_lds16(g_, &dvs[w][(buf_)][p * 256]);                     \
        }                                                                  \
    }

    unsigned u0 = (unsigned)(-(2 * lane));
    float rA0 = BIGF, rB0 = BIGF, rA1 = BIGF;
    float lnL = BIGF, ldL = BIGF;
    float res = 0.0f;

    if constexpr (XPORT) { if (w == 0) STAGE(0, 0); }

    for (int c = 0; c < CTOT; ++c) {
        const int lc = c - c0w;
        if (lc >= 0 && lc < NCH) {
            const int s0c = s0w + lc * K_;
            if constexpr (XPORT) {
                if (lc + 1 < NCH) {
                    STAGE(lc + 1, (lc + 1) & 1);
                    asm volatile("s_waitcnt vmcnt(8)" ::: "memory");
                } else {
                    asm volatile("s_waitcnt vmcnt(0)" ::: "memory");
                }
            }
            float rr[18];
            if constexpr (XPORT) {
                const float4 q0 = *(const float4*)&ringR[s0c - 2];
                const float4 q1 = *(const float4*)&ringR[s0c + 2];
                const float4 q2 = *(const float4*)&ringR[s0c + 6];
                const float4 q3 = *(const float4*)&ringR[s0c + 10];
                const float2 q4 = *(const float2*)&ringR[s0c + 14];
                rr[0] = q0.x; rr[1] = q0.y; rr[2] = q0.z; rr[3] = q0.w;
                rr[4] = q1.x; rr[5] = q1.y; rr[6] = q1.z; rr[7] = q1.w;
                rr[8] = q2.x; rr[9] = q2.y; rr[10] = q2.z; rr[11] = q2.w;
                rr[12] = q3.x; rr[13] = q3.y; rr[14] = q3.z; rr[15] = q3.w;
                rr[16] = q4.x; rr[17] = q4.y;
            } else {
#pragma unroll
                for (int q = 0; q < 18; ++q) rr[q] = BIGF;
            }
            const float* dvb = XPORT ? &dvs[w][lc & 1][0] : nullptr;
            float2 dq[3];
            if constexpr (XPORT) {
                dq[0] = *(const float2*)&dvb[0 * 128 + 2 * lane];
                dq[1] = *(const float2*)&dvb[1 * 128 + 2 * lane];
                dq[2] = *(const float2*)&dvb[2 * 128 + 2 * lane];
            }
            if (lc == 0) {
                lnL = l0 ? rr[1] : BIGF;
                ldL = l0 ? rr[0] : BIGF;
            }
#pragma unroll
            for (int t = 0; t < K_; ++t) {
                float d0, d1;
                if constexpr (XPORT) { d0 = dq[t % 3].x; d1 = dq[t % 3].y; }
                else                 { d0 = dval;        d1 = dval; }
                float r0, r1;
                if constexpr (SOFT) {
                    float m0  = vmin3(rA0, lnL, ldL);
                    float md0 = vmed3(rA0, lnL, ldL);
                    float mx0 = vmax3(rA0, lnL, ldL);
                    float e0 = EXP2((m0 - md0) * C1);
                    float f0 = EXP2((m0 - mx0) * C1);
                    r0 = fmaf(C2, LOG2(1.0f + e0 + f0), m0 + d0);
                    float m1  = vmin3(rA1, rA0, rB0);
                    float md1 = vmed3(rA1, rA0, rB0);
                    float mx1 = vmax3(rA1, rA0, rB0);
                    float e1 = EXP2((m1 - md1) * C1);
                    float f1 = EXP2((m1 - mx1) * C1);
                    r1 = fmaf(C2, LOG2(1.0f + e1 + f1), m1 + d1);
                } else {
                    r0 = vmin3(rA0, lnL, ldL) + d0;
                    r1 = vmin3(rA1, rA0, rB0) + d1;
                }
                res = (u0 == 512u) ? r1 : res;
                u0 += 1u;
                rB0 = rA0; rA0 = r0;
                ldL = lnL;
                float sh = dpp_shr1(r1);
                lnL = l0 ? rr[t + 2] : sh;
                rA1 = r1;
                if constexpr (XPORT) {
                    if (l63) ringW[s0c + t] = r1;
                    if (t + 3 < K_)
                        dq[t % 3] = *(const float2*)&dvb[(t + 3) * 128 + 2 * lane];
                }
            }
        } else if (lc == -1) {
            if constexpr (XPORT) STAGE(0, 0);
        }
        asm volatile("s_waitcnt lgkmcnt(0)" ::: "memory");
        __builtin_amdgcn_s_barrier();
    }
#undef STAGE

    if constexpr (V == 0) {
        if (w == WV - 1 && l63) out[2 * B_ * N_ + b] = res;
    } else {
        asm volatile("" :: "v"(rA0), "v"(rB0), "v"(res));  // keep chain live
        if (w == WV - 1 && l63) dump[b] = res;
    }
}

extern "C" void kernel_launch(void* const* d_in, const int* in_sizes, int n_in,
                              void* d_out, int out_size, void* d_ws, size_t ws_size,
                              hipStream_t stream) {
    const float* x = (const float*)d_in[0];
    const float* y = (const float*)d_in[1];
    float* out = (float*)d_out;
    float* ddiag = (float*)d_ws;  // 8.0 MB; rewritten by dist kernel each call

    dim3 g1(N_ / 16, N_ / 16, B_);
    dist_diag_kernel<<<g1, 256, 0, stream>>>(x, y, ddiag);
    // V0 first (reads clean ddiag, writes d_out) — later probes may dirty ws
    sdtw_probe<0><<<B_, 256, 0, stream>>>(ddiag, out, ddiag);
    sdtw_probe<2><<<B_, 256, 0, stream>>>(ddiag, out, ddiag);
    sdtw_probe<1><<<B_, 256, 0, stream>>>(ddiag, out, ddiag);
    sdtw_probe<3><<<B_, 256, 0, stream>>>(ddiag, out, ddiag);
}

// Round 6
// 133.369 us; speedup vs baseline: 2.4359x; 2.4359x over previous
//
#include <hip/hip_runtime.h>
#include <math.h>
#include <stdint.h>

#define B_ 4
#define N_ 512
#define D_ 64
#define NDIAG (2 * N_ - 1)   // 1023 diagonal rows of D
#define WV 4                 // waves per block
#define K_ 16                // diagonals per chunk (between barriers)
#define DC0 9                // chunk stagger between adjacent waves
#define NCH 40               // chunks per wave
#define CTOT (DC0 * (WV - 1) + NCH)  // 67
#define RING 1028            // non-wrapping ring: one slot per diagonal
#define BIGF 1e30f           // finite border sentinel: BIG + d rounds to BIG

// Phase 1: D[b][i][j] = ||x[b,i,:]-y[b,j,:]||, stored diagonal-major
__global__ __launch_bounds__(256) void dist_diag_kernel(
    const float* __restrict__ x, const float* __restrict__ y,
    float* __restrict__ ddiag)
{
    const int b = blockIdx.z;
    const int i0 = blockIdx.y * 16;
    const int j0 = blockIdx.x * 16;
    __shared__ float xs[16 * 68];
    __shared__ float ys[16 * 68];
    const int t = threadIdx.x;
    const int lr = t >> 4;
    const int lc = t & 15;
    const float4* xsrc = (const float4*)(x + (((size_t)b * N_) + i0 + lr) * D_);
    const float4* ysrc = (const float4*)(y + (((size_t)b * N_) + j0 + lr) * D_);
    *(float4*)(&xs[lr * 68 + lc * 4]) = xsrc[lc];
    *(float4*)(&ys[lr * 68 + lc * 4]) = ysrc[lc];
    __syncthreads();

    const int ti = t >> 4, tj = t & 15;
    const float* xr = &xs[ti * 68];
    const float* yr = &ys[tj * 68];
    float acc = 0.f;
#pragma unroll
    for (int k = 0; k < 16; ++k) {
        float4 a = *(const float4*)(xr + 4 * k);
        float4 c = *(const float4*)(yr + 4 * k);
        float d0 = a.x - c.x, d1 = a.y - c.y, d2 = a.z - c.z, d3 = a.w - c.w;
        acc += d0 * d0 + d1 * d1 + d2 * d2 + d3 * d3;
    }
    const int i = i0 + ti, j = j0 + tj;
    ddiag[((size_t)b * NDIAG + (size_t)(i + j)) * N_ + j] = sqrtf(acc);
}

__device__ __forceinline__ float dpp_shr1(float x) {
    int v = __builtin_amdgcn_update_dpp(0x7f800000, __float_as_int(x),
                                        0x138 /*WAVE_SHR1*/, 0xf, 0xf, false);
    return __int_as_float(v);
}

__device__ __forceinline__ float vmin3(float a, float b, float c) {
    float r; asm("v_min3_f32 %0, %1, %2, %3" : "=v"(r) : "v"(a), "v"(b), "v"(c)); return r;
}
__device__ __forceinline__ float vmed3(float a, float b, float c) {
    float r; asm("v_med3_f32 %0, %1, %2, %3" : "=v"(r) : "v"(a), "v"(b), "v"(c)); return r;
}
__device__ __forceinline__ float vmax3(float a, float b, float c) {
    float r; asm("v_max3_f32 %0, %1, %2, %3" : "=v"(r) : "v"(a), "v"(b), "v"(c)); return r;
}

#if __has_builtin(__builtin_amdgcn_exp2f)
#define EXP2(x) __builtin_amdgcn_exp2f(x)
#else
#define EXP2(x) exp2f(x)
#endif
#if __has_builtin(__builtin_amdgcn_logf)
#define LOG2(x) __builtin_amdgcn_logf(x)
#else
#define LOG2(x) log2f(x)
#endif

// Phase 2: staggered register-resident soft-DTW with REGISTER d-transport.
// R5 ablation: V0(soft+xport)=V2(hard+xport)=141us, V1/V3(no xport)~16us
// -> 88% of time was transport machinery, not math, not structure.
// Here: d comes via asm-volatile global_load_dwordx2 into a 32-deep float2
// register queue (asm loads can't be compiler-sunk like R3, no LDS on the
// chain like R4). One counted vmcnt wait per chunk; keep-alive asm ties
// consumption after the wait (rule #18).
__global__ __launch_bounds__(256) void sdtw_reg_kernel(
    const float* __restrict__ ddiag, float* __restrict__ out)
{
    const int b = blockIdx.x;
    const int tid = threadIdx.x;
    const int w = tid >> 6;
    const int lane = tid & 63;
    const float* Db = ddiag + (size_t)b * (NDIAG * (size_t)N_);

    // deterministic monotone paths: arange(512) for both
    for (int q = tid; q < N_; q += 256) {
        out[b * N_ + q] = (float)q;
        out[B_ * N_ + b * N_ + q] = (float)q;
    }

    __shared__ __align__(16) float ring[WV + 1][RING];
    for (int q = tid; q < (WV + 1) * RING; q += 256)
        (&ring[0][0])[q] = (q == 0) ? 0.0f : BIGF;
    // drain the path stores so vmcnt counts only our asm loads below
    asm volatile("s_waitcnt vmcnt(0)");
    __syncthreads();

    const float C1 = 14.4269504089f;    // (1/gamma)*log2(e)
    const float C2 = -0.069314718056f;  // -gamma*ln(2)
    const int c0w = DC0 * w;
    const int s0w = 128 * w + 2;
    const bool l0 = (lane == 0);
    const bool l63 = (lane == 63);
    const float* ringR = ring[w];
    float* ringW = ring[w + 1];
    // per-lane column base: Db + colbase + 2*lane  (jj0-1)
    const uint64_t dlane = (uint64_t)(Db + 128 * w + 2 * lane);

    unsigned u0 = (unsigned)(-(2 * lane));
    float rA0 = BIGF, rB0 = BIGF, rA1 = BIGF;
    float lnL = BIGF, ldL = BIGF;
    float res = 0.0f;

    float2 vq[2 * K_];  // register d-queue; all indices compile-time

// issue chunk lcn_'s 16 row-loads into queue half half_ (asm: cannot sink)
#define ISSUE16(lcn_, half_)                                                \
    {                                                                       \
        const int s0n_ = s0w + (lcn_) * K_;                                 \
        _Pragma("unroll")                                                   \
        for (int t = 0; t < K_; ++t) {                                      \
            int rown_ = s0n_ - 2 + t;                                       \
            rown_ = rown_ > (NDIAG - 1) ? (NDIAG - 1) : rown_;              \
            uint64_t a_ = dlane + (uint64_t)rown_ * (uint64_t)(N_ * 4);     \
            asm volatile("global_load_dwordx2 %0, %1, off"                  \
                         : "=v"(vq[(half_) * K_ + t]) : "v"(a_));           \
        }                                                                   \
    }

#define TIE8(o_, p_)                                                        \
    asm volatile("" : "+v"(vq[(o_) + (p_) + 0]), "+v"(vq[(o_) + (p_) + 1]), \
                      "+v"(vq[(o_) + (p_) + 2]), "+v"(vq[(o_) + (p_) + 3]), \
                      "+v"(vq[(o_) + (p_) + 4]), "+v"(vq[(o_) + (p_) + 5]), \
                      "+v"(vq[(o_) + (p_) + 6]), "+v"(vq[(o_) + (p_) + 7]))

#define CHUNK(par_)                                                         \
    {                                                                       \
        const int s0c = s0w + lc * K_;                                      \
        constexpr int o_ = (par_) * K_;                                     \
        if (lc + 1 < NCH) {                                                 \
            ISSUE16(lc + 1, 1 - (par_));                                    \
            asm volatile("s_waitcnt vmcnt(16)"); /* current half landed */  \
        } else {                                                            \
            asm volatile("s_waitcnt vmcnt(0)");                             \
        }                                                                   \
        TIE8(o_, 0); TIE8(o_, 8); /* order uses after the wait (r#18) */    \
        float rr[18];                                                       \
        {                                                                   \
            const float4 q0 = *(const float4*)&ringR[s0c - 2];              \
            const float4 q1 = *(const float4*)&ringR[s0c + 2];              \
            const float4 q2 = *(const float4*)&ringR[s0c + 6];              \
            const float4 q3 = *(const float4*)&ringR[s0c + 10];             \
            const float2 q4 = *(const float2*)&ringR[s0c + 14];             \
            rr[0] = q0.x; rr[1] = q0.y; rr[2] = q0.z; rr[3] = q0.w;         \
            rr[4] = q1.x; rr[5] = q1.y; rr[6] = q1.z; rr[7] = q1.w;         \
            rr[8] = q2.x; rr[9] = q2.y; rr[10] = q2.z; rr[11] = q2.w;       \
            rr[12] = q3.x; rr[13] = q3.y; rr[14] = q3.z; rr[15] = q3.w;     \
            rr[16] = q4.x; rr[17] = q4.y;                                   \
        }                                                                   \
        if (lc == 0) {                                                      \
            lnL = l0 ? rr[1] : BIGF;                                        \
            ldL = l0 ? rr[0] : BIGF;                                        \
        }                                                                   \
        _Pragma("unroll")                                                   \
        for (int t = 0; t < K_; ++t) {                                      \
            const float d0 = vq[o_ + t].x, d1 = vq[o_ + t].y;               \
            float m0  = vmin3(rA0, lnL, ldL);                               \
            float md0 = vmed3(rA0, lnL, ldL);                               \
            float mx0 = vmax3(rA0, lnL, ldL);                               \
            float e0 = EXP2((m0 - md0) * C1);                               \
            float f0 = EXP2((m0 - mx0) * C1);                               \
            float r0 = fmaf(C2, LOG2(1.0f + e0 + f0), m0 + d0);             \
            float m1  = vmin3(rA1, rA0, rB0);                               \
            float md1 = vmed3(rA1, rA0, rB0);                               \
            float mx1 = vmax3(rA1, rA0, rB0);                               \
            float e1 = EXP2((m1 - md1) * C1);                               \
            float f1 = EXP2((m1 - mx1) * C1);                               \
            float r1 = fmaf(C2, LOG2(1.0f + e1 + f1), m1 + d1);             \
            res = (u0 == 512u) ? r1 : res;                                  \
            u0 += 1u;                                                       \
            rB0 = rA0; rA0 = r0;                                            \
            ldL = lnL;                                                      \
            float sh = dpp_shr1(r1);                                        \
            lnL = l0 ? rr[t + 2] : sh;                                      \
            rA1 = r1;                                                       \
            if (l63) ringW[s0c + t] = r1;                                   \
        }                                                                   \
    }

    if (w == 0) ISSUE16(0, 0);  // wave-0 prologue (others at lc == -1)

    for (int c = 0; c < CTOT; ++c) {
        const int lc = c - c0w;
        if (lc >= 0 && lc < NCH) {
            if ((lc & 1) == 0) { CHUNK(0) } else { CHUNK(1) }
        } else if (lc == -1) {
            ISSUE16(0, 0);
        }
        // LDS-only drain + barrier (register d-loads stay in flight)
        asm volatile("s_waitcnt lgkmcnt(0)" ::: "memory");
        __builtin_amdgcn_s_barrier();
    }
#undef CHUNK
#undef TIE8
#undef ISSUE16

    // R[512][512] captured by wave 3 / lane 63 at i1 == 512
    if (w == WV - 1 && l63) out[2 * B_ * N_ + b] = res;
}

extern "C" void kernel_launch(void* const* d_in, const int* in_sizes, int n_in,
                              void* d_out, int out_size, void* d_ws, size_t ws_size,
                              hipStream_t stream) {
    const float* x = (const float*)d_in[0];
    const float* y = (const float*)d_in[1];
    float* out = (float*)d_out;
    float* ddiag = (float*)d_ws;  // 4*1023*512*4 B = 8.0 MB

    dim3 g1(N_ / 16, N_ / 16, B_);
    dist_diag_kernel<<<g1, 256, 0, stream>>>(x, y, ddiag);
    sdtw_reg_kernel<<<B_, 256, 0, stream>>>(ddiag, out);
}